// Round 4
// baseline (36.815 us; speedup 1.0000x reference)
//
#include <hip/hip_runtime.h>

#define TREES    256
#define MNODES   1023
#define HD       128
#define VOCAB_SZ 100
#define NCLS     6
#define K1_THREADS 512

typedef __attribute__((ext_vector_type(8))) short  short8;
typedef __attribute__((ext_vector_type(4))) unsigned short ushort4_t;
typedef __attribute__((ext_vector_type(8))) __bf16 bf16x8;
typedef __attribute__((ext_vector_type(4))) float  f32x4;

__device__ __forceinline__ unsigned short f2bf(float f) {
    unsigned int u = __float_as_uint(f);
    u += 0x7FFFu + ((u >> 16) & 1u);          // RNE
    return (unsigned short)(u >> 16);
}
__device__ __forceinline__ float bf2f(unsigned short s) {
    return __uint_as_float(((unsigned int)s) << 16);
}
__device__ __forceinline__ float fast_tanh(float x) {
    float e = __expf(2.0f * x);
    return 1.0f - 2.0f / (e + 1.0f);
}

// ---------------- K1 LDS layout (<= 79.5 KB so 2 blocks/CU fit in 160 KB) ----------------
//  R1   [0, 25600):      tanhE bf16 swz (dead after GW GEMM) -> bufA (<=16 KB)
//  RGW  [25600, 51200):  GW bf16 swz (dead after level-8 pass) -> bufB (<=8 KB)
//  ETBL [51200, 76800):  E bf16 swz (persistent)
//  NT   [76800, 80892):  1023 ints   BH [80896, 81408)
#define OFF_R1    0
#define OFF_GW    25600
#define OFF_ETBL  51200
#define OFF_NT    76800
#define OFF_BH    80896
#define LDS1      81408

__global__ __launch_bounds__(K1_THREADS, 4)
void k1_subtree(const int* __restrict__ node_type,
                const float* __restrict__ E,
                const float* __restrict__ Wh,
                const float* __restrict__ bh,
                float* __restrict__ ws)
{
    __shared__ __align__(16) unsigned char lds[LDS1];
    int*   nt_lds = (int*)(lds + OFF_NT);
    float* bh_lds = (float*)(lds + OFF_BH);

    const int b    = blockIdx.x;
    const int t    = b >> 1;                   // tree
    const int s    = b & 1;                    // which half-subtree (child 1 or 2)
    const int tid  = threadIdx.x;
    const int lane = tid & 63;
    const int wv   = tid >> 6;                 // 8 waves = 4 col-waves x 2 row-groups
    const int l16  = lane & 15;
    const int lg   = lane >> 4;
    const int cw   = wv & 3;
    const int g    = wv >> 2;
    const int ncol0 = cw * 32 + l16;
    const int ncol1 = ncol0 + 16;

    // ---------------- staging (coalesced; no Wh stage) ----------------
    for (int i = tid; i < MNODES; i += K1_THREADS) nt_lds[i] = node_type[t * MNODES + i];
    if (tid < HD) bh_lds[tid] = bh[tid];
    for (int i4 = tid; i4 < VOCAB_SZ * HD / 4; i4 += K1_THREADS) {
        int row = i4 >> 5;
        int c4  = i4 & 31;
        float4 v = ((const float4*)E)[i4];
        ushort4_t e, te;
        e[0] = f2bf(v.x); e[1] = f2bf(v.y); e[2] = f2bf(v.z); e[3] = f2bf(v.w);
        te[0] = f2bf(fast_tanh(v.x)); te[1] = f2bf(fast_tanh(v.y));
        te[2] = f2bf(fast_tanh(v.z)); te[3] = f2bf(fast_tanh(v.w));
        int boff = row * 256 + ((c4 * 8) ^ ((row & 7) << 4));
        *(ushort4_t*)(lds + OFF_ETBL + boff) = e;
        *(ushort4_t*)(lds + OFF_R1   + boff) = te;
    }

    // ---------------- Wh B-fragments straight from global (L2-hot, one-time) ----------------
    bf16x8 bfr[2][4];
    #pragma unroll
    for (int n = 0; n < 2; ++n) {
        int nc = (n == 0) ? ncol0 : ncol1;
        #pragma unroll
        for (int kt = 0; kt < 4; ++kt) {
            short8 sv;
            #pragma unroll
            for (int i = 0; i < 8; ++i) {
                int krow = kt * 32 + lg * 8 + i;
                sv[i] = (short)f2bf(Wh[krow * HD + nc]);
            }
            bfr[n][kt] = __builtin_bit_cast(bf16x8, sv);
        }
    }
    __syncthreads();
    const float bhv0 = bh_lds[ncol0];
    const float bhv1 = bh_lds[ncol1];

    // ---------------- GW = tanh(E) @ Wh  (bf16 out, 7 mtiles split over 2 row-groups) ----
    for (int mt = g; mt < 7; mt += 2) {
        int arow = mt * 16 + l16;
        bf16x8 a[4];
        #pragma unroll
        for (int kt = 0; kt < 4; ++kt) {
            short8 sv = *(const short8*)(lds + OFF_R1 + arow * 256 +
                                         ((kt * 64 + lg * 16) ^ ((arow & 7) << 4)));
            a[kt] = __builtin_bit_cast(bf16x8, sv);
        }
        f32x4 aA0 = {0,0,0,0}, aB0 = {0,0,0,0}, aA1 = {0,0,0,0}, aB1 = {0,0,0,0};
        aA0 = __builtin_amdgcn_mfma_f32_16x16x32_bf16(a[0], bfr[0][0], aA0, 0, 0, 0);
        aB0 = __builtin_amdgcn_mfma_f32_16x16x32_bf16(a[1], bfr[0][1], aB0, 0, 0, 0);
        aA1 = __builtin_amdgcn_mfma_f32_16x16x32_bf16(a[0], bfr[1][0], aA1, 0, 0, 0);
        aB1 = __builtin_amdgcn_mfma_f32_16x16x32_bf16(a[1], bfr[1][1], aB1, 0, 0, 0);
        aA0 = __builtin_amdgcn_mfma_f32_16x16x32_bf16(a[2], bfr[0][2], aA0, 0, 0, 0);
        aB0 = __builtin_amdgcn_mfma_f32_16x16x32_bf16(a[3], bfr[0][3], aB0, 0, 0, 0);
        aA1 = __builtin_amdgcn_mfma_f32_16x16x32_bf16(a[2], bfr[1][2], aA1, 0, 0, 0);
        aB1 = __builtin_amdgcn_mfma_f32_16x16x32_bf16(a[3], bfr[1][3], aB1, 0, 0, 0);
        f32x4 acc0 = aA0 + aB0;
        f32x4 acc1 = aA1 + aB1;
        #pragma unroll
        for (int r = 0; r < 4; ++r) {
            int prow = mt * 16 + lg * 4 + r;   // D row = (lane>>4)*4 + r
            if (prow < VOCAB_SZ) {
                *(short*)(lds + OFF_GW + prow * 256 + ((ncol0 * 2) ^ ((prow & 7) << 4))) =
                    (short)f2bf(acc0[r]);
                *(short*)(lds + OFF_GW + prow * 256 + ((ncol1 * 2) ^ ((prow & 7) << 4))) =
                    (short)f2bf(acc1[r]);
            }
        }
    }
    __syncthreads();

    // ---------------- level-8 pass: h(lam=7 nodes, 128 of them) folded -> 64 agg rows ----
    // global offsets for this subtree: lam-7 nodes start at 255+s*128, lam-8 at 511+s*256
    const int G7 = 255 + s * 128;
    const int G8 = 511 + s * 256;
    #pragma unroll
    for (int it = 0; it < 2; ++it) {
        int idx = it * K1_THREADS + tid;       // 64 lam-6 parents x 16 chunks
        int p   = idx >> 4;
        int c8  = idx & 15;
        int colb = c8 * 16;
        int tyP0 = nt_lds[G7 + 2 * p],     tyP1 = nt_lds[G7 + 2 * p + 1];
        int tyA0 = nt_lds[G8 + 4 * p],     tyA1 = nt_lds[G8 + 4 * p + 1];
        int tyB0 = nt_lds[G8 + 4 * p + 2], tyB1 = nt_lds[G8 + 4 * p + 3];
        short8 e0  = *(const short8*)(lds + OFF_ETBL + tyP0 * 256 + (colb ^ ((tyP0 & 7) << 4)));
        short8 e1  = *(const short8*)(lds + OFF_ETBL + tyP1 * 256 + (colb ^ ((tyP1 & 7) << 4)));
        short8 g00 = *(const short8*)(lds + OFF_GW   + tyA0 * 256 + (colb ^ ((tyA0 & 7) << 4)));
        short8 g01 = *(const short8*)(lds + OFF_GW   + tyA1 * 256 + (colb ^ ((tyA1 & 7) << 4)));
        short8 g10 = *(const short8*)(lds + OFF_GW   + tyB0 * 256 + (colb ^ ((tyB0 & 7) << 4)));
        short8 g11 = *(const short8*)(lds + OFF_GW   + tyB1 * 256 + (colb ^ ((tyB1 & 7) << 4)));
        short8 o;
        #pragma unroll
        for (int u = 0; u < 8; ++u) {
            float bb = bh_lds[c8 * 8 + u];
            float h0 = fast_tanh(bf2f((unsigned short)e0[u]) + bf2f((unsigned short)g00[u]) +
                                 bf2f((unsigned short)g01[u]) + bb);
            float h1 = fast_tanh(bf2f((unsigned short)e1[u]) + bf2f((unsigned short)g10[u]) +
                                 bf2f((unsigned short)g11[u]) + bb);
            o[u] = (short)f2bf(h0 + h1);
        }
        *(short8*)(lds + OFF_R1 + p * 256 + (colb ^ ((p & 7) << 4))) = o;   // bufA
    }
    __syncthreads();

    // ---------------- levels lam = 6 .. 0 (subtree-local) ----------------
    unsigned char* bin  = lds + OFF_R1;
    unsigned char* bout = lds + OFF_GW;        // GW dead now
    for (int lam = 6; lam >= 0; --lam) {
        const int P      = 1 << lam;
        const int Gl     = 2 * P - 1 + s * P;  // global start of this subtree's lam-level
        const int mtiles = (P + 15) >> 4;
        for (int mt = g; mt < mtiles; mt += 2) {
            int arow = mt * 16 + l16;
            bf16x8 a[4];
            #pragma unroll
            for (int kt = 0; kt < 4; ++kt) {
                short8 sv = *(const short8*)(bin + arow * 256 +
                                             ((kt * 64 + lg * 16) ^ ((arow & 7) << 4)));
                a[kt] = __builtin_bit_cast(bf16x8, sv);
            }
            f32x4 aA0 = {0,0,0,0}, aB0 = {0,0,0,0}, aA1 = {0,0,0,0}, aB1 = {0,0,0,0};
            aA0 = __builtin_amdgcn_mfma_f32_16x16x32_bf16(a[0], bfr[0][0], aA0, 0, 0, 0);
            aB0 = __builtin_amdgcn_mfma_f32_16x16x32_bf16(a[1], bfr[0][1], aB0, 0, 0, 0);
            aA1 = __builtin_amdgcn_mfma_f32_16x16x32_bf16(a[0], bfr[1][0], aA1, 0, 0, 0);
            aB1 = __builtin_amdgcn_mfma_f32_16x16x32_bf16(a[1], bfr[1][1], aB1, 0, 0, 0);
            aA0 = __builtin_amdgcn_mfma_f32_16x16x32_bf16(a[2], bfr[0][2], aA0, 0, 0, 0);
            aB0 = __builtin_amdgcn_mfma_f32_16x16x32_bf16(a[3], bfr[0][3], aB0, 0, 0, 0);
            aA1 = __builtin_amdgcn_mfma_f32_16x16x32_bf16(a[2], bfr[1][2], aA1, 0, 0, 0);
            aB1 = __builtin_amdgcn_mfma_f32_16x16x32_bf16(a[3], bfr[1][3], aB1, 0, 0, 0);
            f32x4 acc0 = aA0 + aB0;
            f32x4 acc1 = aA1 + aB1;
            float hp0 = 0.f, hp1 = 0.f;
            #pragma unroll
            for (int r = 0; r < 4; ++r) {
                int prow = mt * 16 + lg * 4 + r;
                if (prow < P) {
                    int ty   = nt_lds[Gl + prow];
                    float x0 = bf2f(*(const unsigned short*)
                                    (lds + OFF_ETBL + ty * 256 + ((ncol0 * 2) ^ ((ty & 7) << 4))));
                    float x1 = bf2f(*(const unsigned short*)
                                    (lds + OFF_ETBL + ty * 256 + ((ncol1 * 2) ^ ((ty & 7) << 4))));
                    float h0 = fast_tanh(x0 + acc0[r] + bhv0);
                    float h1 = fast_tanh(x1 + acc1[r] + bhv1);
                    if (lam == 0) {            // subtree root -> global ws (f32)
                        ws[(t * 2 + s) * HD + ncol0] = h0;
                        ws[(t * 2 + s) * HD + ncol1] = h1;
                    } else if (r & 1) {
                        int orow = prow >> 1;
                        *(short*)(bout + orow * 256 + ((ncol0 * 2) ^ ((orow & 7) << 4))) =
                            (short)f2bf(hp0 + h0);
                        *(short*)(bout + orow * 256 + ((ncol1 * 2) ^ ((orow & 7) << 4))) =
                            (short)f2bf(hp1 + h1);
                    } else {
                        hp0 = h0; hp1 = h1;
                    }
                }
            }
        }
        __syncthreads();
        unsigned char* tmp = bin; bin = bout; bout = tmp;
    }
}

// ---------------- K2: root update (full f32) + classifier head ----------------
__global__ __launch_bounds__(64)
void k2_root(const int* __restrict__ node_type,
             const float* __restrict__ E,
             const float* __restrict__ Wh,
             const float* __restrict__ bh,
             const float* __restrict__ Wc,
             const float* __restrict__ bc,
             const float* __restrict__ ws,
             float* __restrict__ out)
{
    __shared__ float agg[HD];
    const int t    = blockIdx.x;
    const int lane = threadIdx.x;

    const float* w0 = ws + t * 2 * HD;
    agg[lane]      = w0[lane]      + w0[HD + lane];
    agg[lane + 64] = w0[lane + 64] + w0[HD + lane + 64];
    __syncthreads();

    float x0 = 0.f, x1 = 0.f;
    #pragma unroll 8
    for (int k = 0; k < HD; ++k) {
        float a = agg[k];
        x0 += a * Wh[k * HD + lane];
        x1 += a * Wh[k * HD + lane + 64];
    }
    int ty = node_type[t * MNODES];            // root node type
    float h0 = fast_tanh(E[ty * HD + lane]      + x0 + bh[lane]);
    float h1 = fast_tanh(E[ty * HD + lane + 64] + x1 + bh[lane + 64]);

    float lgt[NCLS];
    #pragma unroll
    for (int c = 0; c < NCLS; ++c) {
        float v = h0 * Wc[lane * NCLS + c] + h1 * Wc[(lane + 64) * NCLS + c];
        #pragma unroll
        for (int off = 32; off > 0; off >>= 1)
            v += __shfl_xor(v, off, 64);
        lgt[c] = v + bc[c];
    }
    if (lane == 0) {
        float mx = lgt[0];
        #pragma unroll
        for (int c = 1; c < NCLS; ++c) mx = fmaxf(mx, lgt[c]);
        float sum = 0.f;
        #pragma unroll
        for (int c = 0; c < NCLS; ++c) sum += __expf(lgt[c] - mx);
        float lse = mx + __logf(sum);
        #pragma unroll
        for (int c = 0; c < NCLS; ++c) out[t * NCLS + c] = lgt[c] - lse;
    }
}

extern "C" void kernel_launch(void* const* d_in, const int* in_sizes, int n_in,
                              void* d_out, int out_size, void* d_ws, size_t ws_size,
                              hipStream_t stream) {
    const int*   node_type = (const int*)d_in[0];
    // d_in[1]=parent_idx, d_in[2]=depth, d_in[3]=root_idx: static tree structure, unused
    const float* E  = (const float*)d_in[4];
    const float* Wh = (const float*)d_in[5];
    const float* bh = (const float*)d_in[6];
    const float* Wc = (const float*)d_in[7];
    const float* bc = (const float*)d_in[8];
    float* out = (float*)d_out;
    float* ws  = (float*)d_ws;                 // 256 trees x 2 subtrees x 128 f32 = 256 KB

    k1_subtree<<<dim3(TREES * 2), dim3(K1_THREADS), 0, stream>>>(node_type, E, Wh, bh, ws);
    k2_root   <<<dim3(TREES),     dim3(64),         0, stream>>>(node_type, E, Wh, bh, Wc, bc, ws, out);
}

// Round 5
// 36.299 us; speedup vs baseline: 1.0142x; 1.0142x over previous
//
#include <hip/hip_runtime.h>

#define TREES    256
#define MNODES   1023
#define HD       128
#define VOCAB_SZ 100
#define NCLS     6
#define NTHR     512

typedef __attribute__((ext_vector_type(8))) short  short8;
typedef __attribute__((ext_vector_type(4))) unsigned short ushort4_t;
typedef __attribute__((ext_vector_type(8))) __bf16 bf16x8;
typedef __attribute__((ext_vector_type(4))) float  f32x4;

__device__ __forceinline__ unsigned short f2bf(float f) {
    unsigned int u = __float_as_uint(f);
    u += 0x7FFFu + ((u >> 16) & 1u);          // RNE
    return (unsigned short)(u >> 16);
}
__device__ __forceinline__ float bf2f(unsigned short s) {
    return __uint_as_float(((unsigned int)s) << 16);
}
__device__ __forceinline__ float fast_tanh(float x) {
    float e = __expf(2.0f * x);
    return 1.0f - 2.0f / (e + 1.0f);
}

// LDS layout with lifetime aliasing:
//  [0, 58368):      Wh frags 32 KB + tanhE 25.6 KB  (both dead after GW GEMM / bfr load)
//                   -> 8 per-wave agg bufs x 6144 B (ping 16 rows @0, pong 8 rows @4096)
//  [58368, 83968):  E bf16 swz (persistent)
//  [83968,109568):  GW bf16 swz (dead after L8 pass)
//  then H3 / nt / bh / hroot
#define OFF_WHF   0
#define OFF_TE    32768
#define OFF_WBUF  0
#define OFF_ETBL  58368
#define OFF_GW    83968
#define OFF_H3    109568
#define OFF_NT    111616
#define OFF_BH    115712
#define OFF_HROOT 116224
#define LDS_BYTES 116736

// One level phase: h = tanh(E[ty] + agg@Wh + bh), pairwise-folded into bout.
// MODE 0: fold child pairs -> bout rows; MODE 1: write h (P==1) to H3 row; MODE 2: hroot f32.
template<int P, int MODE>
__device__ __forceinline__ void gemm_phase(
    unsigned char* lds, const unsigned char* bin, unsigned char* bout,
    const bf16x8 (&bfr)[32], const int* nt, int ntOff, const float* bhc,
    int l16, int lg, int h3row, float* hroot)
{
    const int arow = (l16 < P) ? l16 : (P - 1);
    const int aswz = (arow & 7) << 4;
    bf16x8 a[4];
#pragma unroll
    for (int kt = 0; kt < 4; ++kt)
        a[kt] = __builtin_bit_cast(bf16x8,
            *(const short8*)(bin + arow * 256 + ((kt * 64 + lg * 16) ^ aswz)));
    f32x4 acc[8];
#pragma unroll
    for (int ct = 0; ct < 8; ++ct) {
        f32x4 c = {0.f, 0.f, 0.f, 0.f};
#pragma unroll
        for (int kt = 0; kt < 4; ++kt)
            c = __builtin_amdgcn_mfma_f32_16x16x32_bf16(a[kt], bfr[ct * 4 + kt], c, 0, 0, 0);
        acc[ct] = c;
    }
    float hprev[8];
#pragma unroll
    for (int r = 0; r < 4; ++r) {
        const int prow  = lg * 4 + r;          // D row = (lane>>4)*4 + r  [verified m89]
        const bool valid = (prow < P);
        const int ty    = nt[ntOff + (valid ? prow : 0)];
        const int tswz  = (ty & 7) << 4;
#pragma unroll
        for (int ct = 0; ct < 8; ++ct) {
            const int col = ct * 16 + l16;
            float x = bf2f(*(const unsigned short*)
                           (lds + OFF_ETBL + ty * 256 + ((col * 2) ^ tswz)));
            float h = fast_tanh(x + acc[ct][r] + bhc[ct]);
            if (MODE == 0) {
                if (valid) {
                    if (r & 1) {
                        int orow = prow >> 1;
                        *(unsigned short*)(bout + orow * 256 +
                            ((col * 2) ^ ((orow & 7) << 4))) = f2bf(hprev[ct] + h);
                    } else {
                        hprev[ct] = h;
                    }
                }
            } else if (MODE == 1) {
                if (valid)
                    *(unsigned short*)(lds + OFF_H3 + h3row * 256 +
                        ((col * 2) ^ ((h3row & 7) << 4))) = f2bf(h);
            } else {
                if (valid) hroot[col] = h;
            }
        }
    }
}

__global__ __launch_bounds__(NTHR, 2)
void tree_rnn_kernel(const int* __restrict__ node_type,
                     const float* __restrict__ E,
                     const float* __restrict__ Wh,
                     const float* __restrict__ bh,
                     const float* __restrict__ Wc,
                     const float* __restrict__ bc,
                     float* __restrict__ out)
{
    __shared__ __align__(16) unsigned char lds[LDS_BYTES];
    int*   nt     = (int*)(lds + OFF_NT);
    float* bh_lds = (float*)(lds + OFF_BH);
    float* hroot  = (float*)(lds + OFF_HROOT);

    const int t    = blockIdx.x;
    const int tid  = threadIdx.x;
    const int lane = tid & 63;
    const int wv   = tid >> 6;                 // 8 waves, wave = one depth-3 subtree
    const int l16  = lane & 15;
    const int lg   = lane >> 4;

    // ---------------- staging (coalesced) ----------------
    for (int i = tid; i < MNODES; i += NTHR) nt[i] = node_type[t * MNODES + i];
    if (tid < HD) bh_lds[tid] = bh[tid];

    for (int i4 = tid; i4 < VOCAB_SZ * HD / 4; i4 += NTHR) {
        int row = i4 >> 5, c4 = i4 & 31;
        float4 v = ((const float4*)E)[i4];
        ushort4_t e, te;
        e[0] = f2bf(v.x); e[1] = f2bf(v.y); e[2] = f2bf(v.z); e[3] = f2bf(v.w);
        te[0] = f2bf(fast_tanh(v.x)); te[1] = f2bf(fast_tanh(v.y));
        te[2] = f2bf(fast_tanh(v.z)); te[3] = f2bf(fast_tanh(v.w));
        int boff = row * 256 + ((c4 * 8) ^ ((row & 7) << 4));
        *(ushort4_t*)(lds + OFF_ETBL + boff) = e;
        *(ushort4_t*)(lds + OFF_TE   + boff) = te;
    }
    // Wh -> B-fragment layout: frag f=(ct*4+kt), lane l holds Wh[k=kt*32+(l>>4)*8+i][ct*16+(l&15)]
    for (int fid = tid; fid < 2048; fid += NTHR) {
        int l   = fid & 63;
        int kt  = (fid >> 6) & 3;
        int ct  = fid >> 8;
        int col = ct * 16 + (l & 15);
        int k0  = kt * 32 + (l >> 4) * 8;
        short8 s;
#pragma unroll
        for (int i = 0; i < 8; ++i) s[i] = (short)f2bf(Wh[(k0 + i) * HD + col]);
        *(short8*)(lds + OFF_WHF + (fid << 4)) = s;
    }
    __syncthreads();

    // ---------------- whole Wh into registers (128 VGPRs) ----------------
    bf16x8 bfr[32];
#pragma unroll
    for (int f = 0; f < 32; ++f)
        bfr[f] = *(const bf16x8*)(lds + OFF_WHF + ((f * 64 + lane) << 4));
    float bhc[8];
#pragma unroll
    for (int ct = 0; ct < 8; ++ct) bhc[ct] = bh_lds[ct * 16 + l16];

    // ---------------- GW = tanh(E) @ Wh (waves 0..6, one 16-row mtile each) ----------------
    if (wv < 7) {
        const int arow = wv * 16 + l16;
        const int aswz = (arow & 7) << 4;
        bf16x8 a[4];
#pragma unroll
        for (int kt = 0; kt < 4; ++kt)
            a[kt] = __builtin_bit_cast(bf16x8,
                *(const short8*)(lds + OFF_TE + arow * 256 + ((kt * 64 + lg * 16) ^ aswz)));
#pragma unroll
        for (int ct = 0; ct < 8; ++ct) {
            f32x4 c = {0.f, 0.f, 0.f, 0.f};
#pragma unroll
            for (int kt = 0; kt < 4; ++kt)
                c = __builtin_amdgcn_mfma_f32_16x16x32_bf16(a[kt], bfr[ct * 4 + kt], c, 0, 0, 0);
#pragma unroll
            for (int r = 0; r < 4; ++r) {
                int prow = wv * 16 + lg * 4 + r;
                if (prow < VOCAB_SZ)
                    *(unsigned short*)(lds + OFF_GW + prow * 256 +
                        (((ct * 16 + l16) * 2) ^ ((prow & 7) << 4))) = f2bf(c[r]);
            }
        }
    }
    __syncthreads();   // GW ready; Wh-frag + tanhE regions now dead -> become wavebufs

    unsigned char* ping = lds + OFF_WBUF + wv * 6144;
    unsigned char* pong = ping + 4096;

    // ---------------- L8 pass: h8 = tanh(E[ty8]+GW[tyL]+GW[tyR]+bh), fold -> agg7 (16 rows) ----
    {
        const int j  = lane >> 2;              // agg7 row 0..15
        const int c0 = (lane & 3) * 32;        // 32 cols per lane
        const int tyA  = nt[255 + wv * 32 + 2 * j];
        const int tyB  = nt[255 + wv * 32 + 2 * j + 1];
        const int b9   = 511 + wv * 64 + 4 * j;
        const int tyAL = nt[b9], tyAR = nt[b9 + 1], tyBL = nt[b9 + 2], tyBR = nt[b9 + 3];
        const int sA = (tyA & 7) << 4, sB = (tyB & 7) << 4;
        const int sAL = (tyAL & 7) << 4, sAR = (tyAR & 7) << 4;
        const int sBL = (tyBL & 7) << 4, sBR = (tyBR & 7) << 4;
        const int sj = (j & 7) << 4;
#pragma unroll
        for (int q = 0; q < 4; ++q) {
            const int cb = c0 * 2 + q * 16;
            short8 eA  = *(const short8*)(lds + OFF_ETBL + tyA  * 256 + (cb ^ sA));
            short8 eB  = *(const short8*)(lds + OFF_ETBL + tyB  * 256 + (cb ^ sB));
            short8 gAL = *(const short8*)(lds + OFF_GW   + tyAL * 256 + (cb ^ sAL));
            short8 gAR = *(const short8*)(lds + OFF_GW   + tyAR * 256 + (cb ^ sAR));
            short8 gBL = *(const short8*)(lds + OFF_GW   + tyBL * 256 + (cb ^ sBL));
            short8 gBR = *(const short8*)(lds + OFF_GW   + tyBR * 256 + (cb ^ sBR));
            float bhv[8];
            *(float4*)(bhv)     = *(const float4*)(bh_lds + c0 + q * 8);
            *(float4*)(bhv + 4) = *(const float4*)(bh_lds + c0 + q * 8 + 4);
            short8 o;
#pragma unroll
            for (int u = 0; u < 8; ++u) {
                float hA = fast_tanh(bf2f((unsigned short)eA[u]) + bf2f((unsigned short)gAL[u]) +
                                     bf2f((unsigned short)gAR[u]) + bhv[u]);
                float hB = fast_tanh(bf2f((unsigned short)eB[u]) + bf2f((unsigned short)gBL[u]) +
                                     bf2f((unsigned short)gBR[u]) + bhv[u]);
                o[u] = (short)f2bf(hA + hB);
            }
            *(short8*)(ping + j * 256 + (cb ^ sj)) = o;
        }
    }

    // ---------------- wave-serial levels 7..3 (zero barriers) ----------------
    gemm_phase<16, 0>(lds, ping, pong, bfr, nt, 127 + 16 * wv, bhc, l16, lg, 0, nullptr);
    gemm_phase< 8, 0>(lds, pong, ping, bfr, nt,  63 +  8 * wv, bhc, l16, lg, 0, nullptr);
    gemm_phase< 4, 0>(lds, ping, pong, bfr, nt,  31 +  4 * wv, bhc, l16, lg, 0, nullptr);
    gemm_phase< 2, 0>(lds, pong, ping, bfr, nt,  15 +  2 * wv, bhc, l16, lg, 0, nullptr);
    gemm_phase< 1, 1>(lds, ping, nullptr, bfr, nt,  7 +      wv, bhc, l16, lg, wv, nullptr);

    __syncthreads();   // all subtree-root h3 rows in H3
    if (wv != 0) return;

    // ---------------- wave-0 tail: fold H3 -> agg2, levels 2..0, head ----------------
    {
        const int j  = lane >> 4;              // agg2 row 0..3
        const int cb = (lane & 15) * 16;
        const int rA = 2 * j, rB = 2 * j + 1;
        short8 a = *(const short8*)(lds + OFF_H3 + rA * 256 + (cb ^ ((rA & 7) << 4)));
        short8 b = *(const short8*)(lds + OFF_H3 + rB * 256 + (cb ^ ((rB & 7) << 4)));
        short8 o;
#pragma unroll
        for (int u = 0; u < 8; ++u)
            o[u] = (short)f2bf(bf2f((unsigned short)a[u]) + bf2f((unsigned short)b[u]));
        *(short8*)(ping + j * 256 + (cb ^ ((j & 7) << 4))) = o;
    }
    gemm_phase<4, 0>(lds, ping, pong, bfr, nt, 3, bhc, l16, lg, 0, nullptr);
    gemm_phase<2, 0>(lds, pong, ping, bfr, nt, 1, bhc, l16, lg, 0, nullptr);
    gemm_phase<1, 2>(lds, ping, nullptr, bfr, nt, 0, bhc, l16, lg, 0, hroot);

    // head + log_softmax (wave 0)
    {
        float hA = hroot[lane], hB = hroot[lane + 64];
        float lgt[NCLS];
#pragma unroll
        for (int c = 0; c < NCLS; ++c) {
            float v = hA * Wc[lane * NCLS + c] + hB * Wc[(lane + 64) * NCLS + c];
#pragma unroll
            for (int off = 32; off > 0; off >>= 1)
                v += __shfl_xor(v, off, 64);
            lgt[c] = v + bc[c];
        }
        if (lane == 0) {
            float mx = lgt[0];
#pragma unroll
            for (int c = 1; c < NCLS; ++c) mx = fmaxf(mx, lgt[c]);
            float s = 0.f;
#pragma unroll
            for (int c = 0; c < NCLS; ++c) s += __expf(lgt[c] - mx);
            float lse = mx + __logf(s);
#pragma unroll
            for (int c = 0; c < NCLS; ++c) out[t * NCLS + c] = lgt[c] - lse;
        }
    }
}

extern "C" void kernel_launch(void* const* d_in, const int* in_sizes, int n_in,
                              void* d_out, int out_size, void* d_ws, size_t ws_size,
                              hipStream_t stream) {
    const int*   node_type = (const int*)d_in[0];
    // d_in[1]=parent_idx, d_in[2]=depth, d_in[3]=root_idx: static tree structure, unused
    const float* E  = (const float*)d_in[4];
    const float* Wh = (const float*)d_in[5];
    const float* bh = (const float*)d_in[6];
    const float* Wc = (const float*)d_in[7];
    const float* bc = (const float*)d_in[8];
    float* out = (float*)d_out;
    tree_rnn_kernel<<<dim3(TREES), dim3(NTHR), 0, stream>>>(node_type, E, Wh, bh, Wc, bc, out);
}

// Round 6
// 27.197 us; speedup vs baseline: 1.3537x; 1.3347x over previous
//
#include <hip/hip_runtime.h>

#define TREES    256
#define MNODES   1023
#define HD       128
#define VOCAB_SZ 100
#define NCLS     6
#define NTHR     1024

typedef __attribute__((ext_vector_type(8))) short  short8;
typedef __attribute__((ext_vector_type(4))) unsigned short ushort4_t;
typedef __attribute__((ext_vector_type(4))) __bf16 bf16x4;
typedef __attribute__((ext_vector_type(8))) __bf16 bf16x8;
typedef __attribute__((ext_vector_type(4))) float  f32x4;

__device__ __forceinline__ unsigned short f2bf(float f) {
    unsigned int u = __float_as_uint(f);
    u += 0x7FFFu + ((u >> 16) & 1u);          // RNE
    return (unsigned short)(u >> 16);
}
__device__ __forceinline__ float bf2f(unsigned short s) {
    return __uint_as_float(((unsigned int)s) << 16);
}
__device__ __forceinline__ float fast_tanh(float x) {
    float e = __expf(2.0f * x);
    return 1.0f - 2.0f / (e + 1.0f);
}

// LDS layout (89 KB), lifetime aliasing:
//  R1 [0,32768):      tanhE bf16 swz (dead after GW GEMM) -> agg ping (<=128 rows)
//  R2 [32768,58368):  GW bf16 swz (dead after L8 pass)    -> agg pong (<=64 rows)
//  ETBL persistent; nt; bh; hroot
#define OFF_R1    0
#define OFF_R2    32768
#define OFF_ETBL  58368
#define OFF_NT    83968
#define OFF_BH    88064
#define OFF_HROOT 88576
#define LDS_BYTES 89088

// Swapped-operand level phase: D[n][p] = sum_k Wh[k][n]*agg[p][k]; lane col = parent p.
// MODE 0: h = tanh(E+D+bh), fold parent pairs via shfl_xor -> bout. MODE 1: root -> hroot f32.
template<int P, int MODE>
__device__ __forceinline__ void level_phase(
    unsigned char* lds, const unsigned char* bin, unsigned char* bout,
    const bf16x8 (&aT)[8], const float (&bhr)[8], const int* nt, int Loff,
    int cw, int l16, int lg, int g, float* hroot)
{
    constexpr int NBT = (P + 15) / 16;
    for (int bt = g; bt < NBT; bt += 4) {
        const int pb = bt * 16;
        const int p  = pb + l16;
        const int pc = (p < P) ? p : (P - 1);
        const int bswz = (pc & 7) << 4;
        bf16x8 bfrag[4];
#pragma unroll
        for (int kt = 0; kt < 4; ++kt)
            bfrag[kt] = __builtin_bit_cast(bf16x8,
                *(const short8*)(bin + pc * 256 + ((kt * 64 + lg * 16) ^ bswz)));
        f32x4 acc0 = {0.f, 0.f, 0.f, 0.f};
        f32x4 acc1 = {0.f, 0.f, 0.f, 0.f};
#pragma unroll
        for (int kt = 0; kt < 4; ++kt) {
            acc0 = __builtin_amdgcn_mfma_f32_16x16x32_bf16(aT[kt],     bfrag[kt], acc0, 0, 0, 0);
            acc1 = __builtin_amdgcn_mfma_f32_16x16x32_bf16(aT[4 + kt], bfrag[kt], acc1, 0, 0, 0);
        }
        const int ty   = nt[Loff + pc];
        const int tswz = (ty & 7) << 4;
        float h[8];
#pragma unroll
        for (int n2 = 0; n2 < 2; ++n2) {
            const int n0 = cw * 32 + n2 * 16 + lg * 4;
            const uint2 ev = *(const uint2*)(lds + OFF_ETBL + ty * 256 + ((n0 * 2) ^ tswz));
            const f32x4 a = n2 ? acc1 : acc0;
            h[n2*4+0] = fast_tanh(bf2f((unsigned short)(ev.x & 0xffffu)) + a[0] + bhr[n2*4+0]);
            h[n2*4+1] = fast_tanh(bf2f((unsigned short)(ev.x >> 16))     + a[1] + bhr[n2*4+1]);
            h[n2*4+2] = fast_tanh(bf2f((unsigned short)(ev.y & 0xffffu)) + a[2] + bhr[n2*4+2]);
            h[n2*4+3] = fast_tanh(bf2f((unsigned short)(ev.y >> 16))     + a[3] + bhr[n2*4+3]);
        }
        if (MODE == 1) {
            if (l16 == 0) {
#pragma unroll
                for (int n2 = 0; n2 < 2; ++n2) {
                    const int n0 = cw * 32 + n2 * 16 + lg * 4;
                    float4 v = {h[n2*4+0], h[n2*4+1], h[n2*4+2], h[n2*4+3]};
                    *(float4*)(hroot + n0) = v;
                }
            }
        } else {
#pragma unroll
            for (int u = 0; u < 8; ++u) h[u] += __shfl_xor(h[u], 1, 64);
            if ((p < P) && !(l16 & 1)) {
                const int orow = (pb >> 1) + (l16 >> 1);
                const int oswz = (orow & 7) << 4;
#pragma unroll
                for (int n2 = 0; n2 < 2; ++n2) {
                    const int n0 = cw * 32 + n2 * 16 + lg * 4;
                    bf16x4 pk = {(__bf16)h[n2*4+0], (__bf16)h[n2*4+1],
                                 (__bf16)h[n2*4+2], (__bf16)h[n2*4+3]};
                    *(bf16x4*)(bout + orow * 256 + ((n0 * 2) ^ oswz)) = pk;
                }
            }
        }
    }
}

__global__ __launch_bounds__(NTHR, 4)
void tree_rnn_kernel(const int* __restrict__ node_type,
                     const float* __restrict__ E,
                     const float* __restrict__ Wh,
                     const float* __restrict__ bh,
                     const float* __restrict__ Wc,
                     const float* __restrict__ bc,
                     float* __restrict__ out)
{
    __shared__ __align__(16) unsigned char lds[LDS_BYTES];
    int*   nt     = (int*)(lds + OFF_NT);
    float* bh_lds = (float*)(lds + OFF_BH);
    float* hroot  = (float*)(lds + OFF_HROOT);

    const int t    = blockIdx.x;
    const int tid  = threadIdx.x;
    const int lane = tid & 63;
    const int wv   = tid >> 6;                 // 16 waves = 4 col-waves x 4 groups
    const int l16  = lane & 15;
    const int lg   = lane >> 4;
    const int cw   = wv & 3;                   // owns output cols [cw*32, cw*32+32)
    const int g    = wv >> 2;                  // parent-btile group

    // ---------------- staging (coalesced) ----------------
    if (tid < MNODES) nt[tid] = node_type[t * MNODES + tid];
    if (tid < HD)     bh_lds[tid] = bh[tid];
    for (int i4 = tid; i4 < VOCAB_SZ * HD / 4; i4 += NTHR) {
        int row = i4 >> 5, c4 = i4 & 31;
        float4 v = ((const float4*)E)[i4];
        ushort4_t e, te;
        e[0] = f2bf(v.x); e[1] = f2bf(v.y); e[2] = f2bf(v.z); e[3] = f2bf(v.w);
        te[0] = f2bf(fast_tanh(v.x)); te[1] = f2bf(fast_tanh(v.y));
        te[2] = f2bf(fast_tanh(v.z)); te[3] = f2bf(fast_tanh(v.w));
        int boff = row * 256 + ((c4 * 8) ^ ((row & 7) << 4));
        *(ushort4_t*)(lds + OFF_ETBL + boff) = e;
        *(ushort4_t*)(lds + OFF_R1   + boff) = te;
    }

    // ---- Wh^T A-fragments straight from global (L2-hot, one-time) + per-lane bh ----
    bf16x8 aT[8];
    float  bhr[8];
#pragma unroll
    for (int n2 = 0; n2 < 2; ++n2) {
        const int col = cw * 32 + n2 * 16 + l16;
#pragma unroll
        for (int kt = 0; kt < 4; ++kt) {
            const int k0 = kt * 32 + lg * 8;
            short8 sv;
#pragma unroll
            for (int i = 0; i < 8; ++i) sv[i] = (short)f2bf(Wh[(k0 + i) * HD + col]);
            aT[n2 * 4 + kt] = __builtin_bit_cast(bf16x8, sv);
        }
        const int nb = cw * 32 + n2 * 16 + lg * 4;
#pragma unroll
        for (int r = 0; r < 4; ++r) bhr[n2 * 4 + r] = bh[nb + r];
    }
    __syncthreads();                                          // b1: stage done

    // ---------------- GW[ty][n] = (tanhE @ Wh)[ty][n], swapped GEMM ----------------
    for (int bt = g; bt < 7; bt += 4) {
        const int tyr = bt * 16 + l16;
        const int tyc = (tyr < VOCAB_SZ) ? tyr : (VOCAB_SZ - 1);
        const int bswz = (tyc & 7) << 4;
        bf16x8 bfrag[4];
#pragma unroll
        for (int kt = 0; kt < 4; ++kt)
            bfrag[kt] = __builtin_bit_cast(bf16x8,
                *(const short8*)(lds + OFF_R1 + tyc * 256 + ((kt * 64 + lg * 16) ^ bswz)));
        f32x4 acc0 = {0.f, 0.f, 0.f, 0.f};
        f32x4 acc1 = {0.f, 0.f, 0.f, 0.f};
#pragma unroll
        for (int kt = 0; kt < 4; ++kt) {
            acc0 = __builtin_amdgcn_mfma_f32_16x16x32_bf16(aT[kt],     bfrag[kt], acc0, 0, 0, 0);
            acc1 = __builtin_amdgcn_mfma_f32_16x16x32_bf16(aT[4 + kt], bfrag[kt], acc1, 0, 0, 0);
        }
        if (tyr < VOCAB_SZ) {
            const int tswz = (tyr & 7) << 4;
#pragma unroll
            for (int n2 = 0; n2 < 2; ++n2) {
                const f32x4 a = n2 ? acc1 : acc0;
                const int n0 = cw * 32 + n2 * 16 + lg * 4;
                bf16x4 pk = {(__bf16)a[0], (__bf16)a[1], (__bf16)a[2], (__bf16)a[3]};
                *(bf16x4*)(lds + OFF_R2 + tyr * 256 + ((n0 * 2) ^ tswz)) = pk;
            }
        }
    }
    __syncthreads();                                          // b2: GW ready

    // ---- L8 pass: h8 = tanh(E[ty8]+GW[tyL]+GW[tyR]+bh), fold pairs -> agg7 (128 rows, R1) ----
#pragma unroll
    for (int it = 0; it < 2; ++it) {
        int idx = it * NTHR + tid;             // 128 parents x 16 chunks
        int j   = idx >> 4;
        int c8  = idx & 15;
        int colb = c8 * 16;
        int tyP0 = nt[255 + 2 * j], tyP1 = nt[256 + 2 * j];
        int b9   = 511 + 4 * j;
        int tyAL = nt[b9], tyAR = nt[b9 + 1], tyBL = nt[b9 + 2], tyBR = nt[b9 + 3];
        short8 e0  = *(const short8*)(lds + OFF_ETBL + tyP0 * 256 + (colb ^ ((tyP0 & 7) << 4)));
        short8 e1  = *(const short8*)(lds + OFF_ETBL + tyP1 * 256 + (colb ^ ((tyP1 & 7) << 4)));
        short8 gAL = *(const short8*)(lds + OFF_R2   + tyAL * 256 + (colb ^ ((tyAL & 7) << 4)));
        short8 gAR = *(const short8*)(lds + OFF_R2   + tyAR * 256 + (colb ^ ((tyAR & 7) << 4)));
        short8 gBL = *(const short8*)(lds + OFF_R2   + tyBL * 256 + (colb ^ ((tyBL & 7) << 4)));
        short8 gBR = *(const short8*)(lds + OFF_R2   + tyBR * 256 + (colb ^ ((tyBR & 7) << 4)));
        float bhv[8];
        *(float4*)(bhv)     = *(const float4*)(bh_lds + c8 * 8);
        *(float4*)(bhv + 4) = *(const float4*)(bh_lds + c8 * 8 + 4);
        short8 o;
#pragma unroll
        for (int u = 0; u < 8; ++u) {
            float hA = fast_tanh(bf2f((unsigned short)e0[u]) + bf2f((unsigned short)gAL[u]) +
                                 bf2f((unsigned short)gAR[u]) + bhv[u]);
            float hB = fast_tanh(bf2f((unsigned short)e1[u]) + bf2f((unsigned short)gBL[u]) +
                                 bf2f((unsigned short)gBR[u]) + bhv[u]);
            o[u] = (short)f2bf(hA + hB);
        }
        *(short8*)(lds + OFF_R1 + j * 256 + (colb ^ ((j & 7) << 4))) = o;
    }
    __syncthreads();                                          // b3: agg7 ready (GW dead)

    // ---------------- levels 7..0, ping-pong R1/R2 ----------------
    unsigned char* R1 = lds + OFF_R1;
    unsigned char* R2 = lds + OFF_R2;
    level_phase<128, 0>(lds, R1, R2, aT, bhr, nt, 127, cw, l16, lg, g, hroot); __syncthreads();
    level_phase< 64, 0>(lds, R2, R1, aT, bhr, nt,  63, cw, l16, lg, g, hroot); __syncthreads();
    level_phase< 32, 0>(lds, R1, R2, aT, bhr, nt,  31, cw, l16, lg, g, hroot); __syncthreads();
    level_phase< 16, 0>(lds, R2, R1, aT, bhr, nt,  15, cw, l16, lg, g, hroot); __syncthreads();
    level_phase<  8, 0>(lds, R1, R2, aT, bhr, nt,   7, cw, l16, lg, g, hroot); __syncthreads();
    level_phase<  4, 0>(lds, R2, R1, aT, bhr, nt,   3, cw, l16, lg, g, hroot); __syncthreads();
    level_phase<  2, 0>(lds, R1, R2, aT, bhr, nt,   1, cw, l16, lg, g, hroot); __syncthreads();
    level_phase<  1, 1>(lds, R2, R1, aT, bhr, nt,   0, cw, l16, lg, g, hroot); __syncthreads();

    // ---------------- classifier head + log_softmax (wave 0) ----------------
    if (tid < 64) {
        float hA = hroot[tid];
        float hB = hroot[tid + 64];
        float lgt[NCLS];
#pragma unroll
        for (int c = 0; c < NCLS; ++c) {
            float v = hA * Wc[tid * NCLS + c] + hB * Wc[(tid + 64) * NCLS + c];
#pragma unroll
            for (int off = 32; off > 0; off >>= 1)
                v += __shfl_xor(v, off, 64);
            lgt[c] = v + bc[c];
        }
        if (tid == 0) {
            float mx = lgt[0];
#pragma unroll
            for (int c = 1; c < NCLS; ++c) mx = fmaxf(mx, lgt[c]);
            float s = 0.f;
#pragma unroll
            for (int c = 0; c < NCLS; ++c) s += __expf(lgt[c] - mx);
            float lse = mx + __logf(s);
#pragma unroll
            for (int c = 0; c < NCLS; ++c) out[t * NCLS + c] = lgt[c] - lse;
        }
    }
}

extern "C" void kernel_launch(void* const* d_in, const int* in_sizes, int n_in,
                              void* d_out, int out_size, void* d_ws, size_t ws_size,
                              hipStream_t stream) {
    const int*   node_type = (const int*)d_in[0];
    // d_in[1]=parent_idx, d_in[2]=depth, d_in[3]=root_idx: static tree structure, unused
    const float* E  = (const float*)d_in[4];
    const float* Wh = (const float*)d_in[5];
    const float* bh = (const float*)d_in[6];
    const float* Wc = (const float*)d_in[7];
    const float* bc = (const float*)d_in[8];
    float* out = (float*)d_out;
    tree_rnn_kernel<<<dim3(TREES), dim3(NTHR), 0, stream>>>(node_type, E, Wh, bh, Wc, bc, out);
}